// Round 1
// baseline (1841.373 us; speedup 1.0000x reference)
//
#include <hip/hip_runtime.h>
#include <hip/hip_bf16.h>

#define NVOC 50257
#define DIM 256
#define HID 256
#define NLAYER 2
#define SEQ 128
#define BATCH 16

typedef __bf16 bf16x8 __attribute__((ext_vector_type(8)));
typedef float f32x4 __attribute__((ext_vector_type(4)));
typedef unsigned short u16;

// ---------------- prep: dec_w f32 -> bf16, zero sync flags ----------------
__global__ void prep_kernel(const float* __restrict__ dw, u16* __restrict__ dwb,
                            unsigned int* __restrict__ flags, int n4) {
  if (blockIdx.x == 0) {
    for (int j = threadIdx.x; j < NLAYER * SEQ * 4; j += blockDim.x) flags[j] = 0u;
  }
  int tid = blockIdx.x * blockDim.x + threadIdx.x;
  int stride = gridDim.x * blockDim.x;
  for (int i = tid; i < n4; i += stride) {
    float4 v = reinterpret_cast<const float4*>(dw)[i];
    __bf16 a = (__bf16)v.x, b = (__bf16)v.y, c = (__bf16)v.z, d = (__bf16)v.w;
    ushort4 o;
    o.x = __builtin_bit_cast(u16, a);
    o.y = __builtin_bit_cast(u16, b);
    o.z = __builtin_bit_cast(u16, c);
    o.w = __builtin_bit_cast(u16, d);
    reinterpret_cast<ushort4*>(dwb)[i] = o;
  }
}

// ---------------- persistent LSTM ----------------
// 8 blocks x 512 threads. Block bx: layer l = bx>>2, slice jj = bx&3 (64 cols/gate).
// Wave w (0..7): gate = w>>1, half = w&1 (32 within-gate cols).
// B = stacked [W(256) ; U(256)] (K=512), held in registers as MFMA fragments.
__global__ __launch_bounds__(512, 1) void lstm_kernel(
    const int* __restrict__ tokp, const float* __restrict__ embp,
    const float* __restrict__ wF, const float* __restrict__ uF, const float* __restrict__ bF,
    const float* __restrict__ wI, const float* __restrict__ uI, const float* __restrict__ bI,
    const float* __restrict__ wC, const float* __restrict__ uC, const float* __restrict__ bC,
    const float* __restrict__ wO, const float* __restrict__ uO, const float* __restrict__ bO,
    float* __restrict__ h0hist, float* __restrict__ h1hist, u16* __restrict__ htopb,
    unsigned int* __restrict__ flags, float* __restrict__ dout)
{
  const int tid  = threadIdx.x;
  const int lane = tid & 63;
  const int wv   = tid >> 6;        // 0..7
  const int bx   = blockIdx.x;      // 0..7
  const int l    = bx >> 2;         // layer
  const int jj   = bx & 3;          // col-slice
  const int gate = wv >> 1;         // 0:f 1:i 2:c(g) 3:o
  const int r16  = lane & 15;
  const int kgrp = lane >> 4;       // 0..3

  const float* Wg[4] = {wF, wI, wC, wO};
  const float* Ug[4] = {uF, uI, uC, uO};
  const float* Bg[4] = {bF, bI, bC, bO};

  // ---- gather B fragments (weights) into registers, f32 -> bf16 ----
  bf16x8 bw[2][16];
  float bias[2];
  {
    const float* W = Wg[gate];
    const float* U = Ug[gate];
#pragma unroll
    for (int nt = 0; nt < 2; ++nt) {
      const int n = jj * 64 + (wv & 1) * 32 + nt * 16 + r16;   // within-gate col
      bias[nt] = Bg[gate][n];
#pragma unroll
      for (int kk = 0; kk < 16; ++kk) {
        const int kb = (kk & 7) * 32 + kgrp * 8;               // k base within 256
        const float* src = (kk < 8) ? (W + (size_t)kb * HID + n)
                                    : (U + (size_t)kb * HID + n);
        bf16x8 v;
#pragma unroll
        for (int e = 0; e < 8; ++e) v[e] = (__bf16)src[(size_t)e * HID];
        bw[nt][kk] = v;
      }
    }
  }

  __shared__ float gbuf[4][16][66];   // [gate][batch][col64] (+pad)

  float* hist = (l == 0) ? h0hist : h1hist;

  // epilogue element ownership: (batch eb, cols ec, ec+1)
  const int eb = tid >> 5;
  const int ec = (tid & 31) * 2;
  float c0 = 0.f, c1 = 0.f;

  for (int t = 0; t < SEQ; ++t) {
    // ---- wait for producers (thread 0 polls, barrier releases WG) ----
    if (tid == 0) {
      if (t > 0) {
        unsigned int* f = flags + (size_t)(l * SEQ + (t - 1)) * 4;
        for (;;) {
          unsigned s = 0;
#pragma unroll
          for (int j = 0; j < 4; ++j)
            s += __hip_atomic_load(f + j, __ATOMIC_ACQUIRE, __HIP_MEMORY_SCOPE_AGENT);
          if (s == 4) break;
        }
      }
      if (l == 1) {
        unsigned int* f = flags + (size_t)(0 * SEQ + t) * 4;
        for (;;) {
          unsigned s = 0;
#pragma unroll
          for (int j = 0; j < 4; ++j)
            s += __hip_atomic_load(f + j, __ATOMIC_ACQUIRE, __HIP_MEMORY_SCOPE_AGENT);
          if (s == 4) break;
        }
      }
    }
    __syncthreads();

    // ---- A = [h_prev(16x256) ; x(16x256)],  acc = A @ Bslice ----
    f32x4 acc0 = {0.f, 0.f, 0.f, 0.f};
    f32x4 acc1 = {0.f, 0.f, 0.f, 0.f};

    int tok = 0;
    if (l == 0) tok = tokp[t * BATCH + r16];
    const float* xbase = (l == 0)
        ? (embp + (size_t)tok * DIM)
        : (h0hist + ((size_t)t * BATCH + r16) * HID);
    const int tp = (t > 0) ? (t - 1) : 0;
    const float* hbase = hist + ((size_t)tp * BATCH + r16) * HID;

#pragma unroll
    for (int kk = 0; kk < 16; ++kk) {
      const int kb = (kk & 7) * 32 + kgrp * 8;
      bf16x8 a;
      if (kk < 8) {
        if (t == 0) {
#pragma unroll
          for (int e = 0; e < 8; ++e) a[e] = (__bf16)0.f;
        } else {
          const float4 u0 = *reinterpret_cast<const float4*>(hbase + kb);
          const float4 u1 = *reinterpret_cast<const float4*>(hbase + kb + 4);
          a[0] = (__bf16)u0.x; a[1] = (__bf16)u0.y; a[2] = (__bf16)u0.z; a[3] = (__bf16)u0.w;
          a[4] = (__bf16)u1.x; a[5] = (__bf16)u1.y; a[6] = (__bf16)u1.z; a[7] = (__bf16)u1.w;
        }
      } else {
        const float4 u0 = *reinterpret_cast<const float4*>(xbase + kb);
        const float4 u1 = *reinterpret_cast<const float4*>(xbase + kb + 4);
        a[0] = (__bf16)u0.x; a[1] = (__bf16)u0.y; a[2] = (__bf16)u0.z; a[3] = (__bf16)u0.w;
        a[4] = (__bf16)u1.x; a[5] = (__bf16)u1.y; a[6] = (__bf16)u1.z; a[7] = (__bf16)u1.w;
      }
      acc0 = __builtin_amdgcn_mfma_f32_16x16x32_bf16(a, bw[0][kk], acc0, 0, 0, 0);
      acc1 = __builtin_amdgcn_mfma_f32_16x16x32_bf16(a, bw[1][kk], acc1, 0, 0, 0);
    }

    // ---- activations -> LDS (C layout: col=lane&15, row=(lane>>4)*4+r) ----
#pragma unroll
    for (int nt = 0; nt < 2; ++nt) {
      const f32x4 acc = nt ? acc1 : acc0;
      const int c = (wv & 1) * 32 + nt * 16 + r16;
#pragma unroll
      for (int r = 0; r < 4; ++r) {
        const float z = acc[r] + bias[nt];
        const float act = (gate == 2) ? tanhf(z) : 1.f / (1.f + expf(-z));
        gbuf[gate][kgrp * 4 + r][c] = act;
      }
    }
    __syncthreads();

    // ---- c/h update: 2 elements per thread ----
    const float ff0 = gbuf[0][eb][ec], ff1 = gbuf[0][eb][ec + 1];
    const float ii0 = gbuf[1][eb][ec], ii1 = gbuf[1][eb][ec + 1];
    const float gg0 = gbuf[2][eb][ec], gg1 = gbuf[2][eb][ec + 1];
    const float oo0 = gbuf[3][eb][ec], oo1 = gbuf[3][eb][ec + 1];
    c0 = ff0 * c0 + ii0 * gg0;
    c1 = ff1 * c1 + ii1 * gg1;
    const float hv0 = oo0 * tanhf(c0);
    const float hv1 = oo1 * tanhf(c1);
    const int n = jj * 64 + ec;
    float* hdst = hist + ((size_t)t * BATCH + eb) * HID + n;
    hdst[0] = hv0; hdst[1] = hv1;
    if (l == 1) {
      u16* hb = htopb + ((size_t)t * BATCH + eb) * HID + n;
      __bf16 b0 = (__bf16)hv0, b1 = (__bf16)hv1;
      hb[0] = __builtin_bit_cast(u16, b0);
      hb[1] = __builtin_bit_cast(u16, b1);
    }
    if (t == SEQ - 1) {
      const size_t logitsN = (size_t)SEQ * BATCH * NVOC;
      float* hT = dout + logitsN + ((size_t)l * BATCH + eb) * HID + n;
      float* cT = dout + logitsN + (size_t)NLAYER * BATCH * HID + ((size_t)l * BATCH + eb) * HID + n;
      hT[0] = hv0; hT[1] = hv1;
      cT[0] = c0;  cT[1] = c1;
    }
    __syncthreads();
    if (tid == 0) {
      __threadfence();  // agent-scope: flush this XCD's dirty L2 lines
      __hip_atomic_store(flags + (size_t)(l * SEQ + t) * 4 + jj, 1u,
                         __ATOMIC_RELEASE, __HIP_MEMORY_SCOPE_AGENT);
    }
  }
}

// ---------------- decoder: logits = h_top @ dec_w^T + dec_b ----------------
// grid (128 M-tiles, 197 N-chunks); 4 waves/WG, each wave: 16(M) x 64(N), K=256.
__global__ __launch_bounds__(256) void dec_kernel(
    const u16* __restrict__ htb, const u16* __restrict__ dwb,
    const float* __restrict__ dbp, float* __restrict__ out)
{
  const int tid  = threadIdx.x;
  const int lane = tid & 63;
  const int wv   = tid >> 6;
  const int r16  = lane & 15;
  const int kgrp = lane >> 4;
  const int m0 = blockIdx.x * 16;
  const int n0 = blockIdx.y * 256 + wv * 64;

  bf16x8 a[8];
  const u16* ap = htb + ((size_t)(m0 + r16)) * HID + kgrp * 8;
#pragma unroll
  for (int kk = 0; kk < 8; ++kk)
    a[kk] = *reinterpret_cast<const bf16x8*>(ap + kk * 32);

  f32x4 acc[4];
#pragma unroll
  for (int nt = 0; nt < 4; ++nt) { acc[nt][0] = 0.f; acc[nt][1] = 0.f; acc[nt][2] = 0.f; acc[nt][3] = 0.f; }

#pragma unroll
  for (int nt = 0; nt < 4; ++nt) {
    const int v = n0 + nt * 16 + r16;
    const int vc = (v < NVOC) ? v : 0;
    const u16* bp = dwb + (size_t)vc * HID + kgrp * 8;
#pragma unroll
    for (int kk = 0; kk < 8; ++kk) {
      bf16x8 b = *reinterpret_cast<const bf16x8*>(bp + kk * 32);
      acc[nt] = __builtin_amdgcn_mfma_f32_16x16x32_bf16(a[kk], b, acc[nt], 0, 0, 0);
    }
  }

#pragma unroll
  for (int nt = 0; nt < 4; ++nt) {
    const int v = n0 + nt * 16 + r16;
    if (v < NVOC) {
      const float bb = dbp[v];
#pragma unroll
      for (int r = 0; r < 4; ++r) {
        const int row = m0 + kgrp * 4 + r;
        out[(size_t)row * NVOC + v] = acc[nt][r] + bb;
      }
    }
  }
}

extern "C" void kernel_launch(void* const* d_in, const int* in_sizes, int n_in,
                              void* d_out, int out_size, void* d_ws, size_t ws_size,
                              hipStream_t stream) {
  const int*   tokp = (const int*)d_in[0];
  const float* embp = (const float*)d_in[1];
  const float* wF = (const float*)d_in[2];
  const float* uF = (const float*)d_in[3];
  const float* bF = (const float*)d_in[4];
  const float* wI = (const float*)d_in[5];
  const float* uI = (const float*)d_in[6];
  const float* bI = (const float*)d_in[7];
  const float* wC = (const float*)d_in[8];
  const float* uC = (const float*)d_in[9];
  const float* bC = (const float*)d_in[10];
  const float* wO = (const float*)d_in[11];
  const float* uO = (const float*)d_in[12];
  const float* bO = (const float*)d_in[13];
  const float* dw = (const float*)d_in[14];
  const float* db = (const float*)d_in[15];
  float* out = (float*)d_out;

  char* ws = (char*)d_ws;
  size_t off = 0;
  u16* dwb = (u16*)(ws + off);  off += (size_t)NVOC * HID * 2;
  off = (off + 255) & ~(size_t)255;
  float* h0   = (float*)(ws + off); off += (size_t)SEQ * BATCH * HID * 4;
  float* h1   = (float*)(ws + off); off += (size_t)SEQ * BATCH * HID * 4;
  u16*   htb  = (u16*)(ws + off);   off += (size_t)SEQ * BATCH * HID * 2;
  unsigned int* flags = (unsigned int*)(ws + off); off += (size_t)NLAYER * SEQ * 4 * 4;

  prep_kernel<<<2048, 256, 0, stream>>>(dw, dwb, flags, NVOC * HID / 4);
  lstm_kernel<<<8, 512, 0, stream>>>(tokp, embp, wF, uF, bF, wI, uI, bI,
                                     wC, uC, bC, wO, uO, bO,
                                     h0, h1, htb, flags, out);
  dec_kernel<<<dim3(128, (NVOC + 255) / 256), 256, 0, stream>>>(htb, dwb, db, out);
}

// Round 2
// 1153.764 us; speedup vs baseline: 1.5960x; 1.5960x over previous
//
#include <hip/hip_runtime.h>
#include <hip/hip_bf16.h>

#define NVOC 50257
#define DIM 256
#define HID 256
#define NLAYER 2
#define SEQ 128
#define BATCH 16

typedef __bf16 bf16x8 __attribute__((ext_vector_type(8)));
typedef float f32x4 __attribute__((ext_vector_type(4)));
typedef unsigned short u16;
typedef unsigned int u32;

// ---------------- prep: dec_w f32 -> bf16 ----------------
__global__ void prep_kernel(const float* __restrict__ dw, u16* __restrict__ dwb, int n4) {
  int tid = blockIdx.x * blockDim.x + threadIdx.x;
  int stride = gridDim.x * blockDim.x;
  for (int i = tid; i < n4; i += stride) {
    float4 v = reinterpret_cast<const float4*>(dw)[i];
    ushort4 o;
    o.x = __builtin_bit_cast(u16, (__bf16)v.x);
    o.y = __builtin_bit_cast(u16, (__bf16)v.y);
    o.z = __builtin_bit_cast(u16, (__bf16)v.z);
    o.w = __builtin_bit_cast(u16, (__bf16)v.w);
    reinterpret_cast<ushort4*>(dwb)[i] = o;
  }
}

// ---------------- XU precompute: XU[t*16+b][g*256+c] = emb[tok] @ U_g  ----------------
// M=2048 (t,b), N=1024 (4 gates x 256), K=256. Block: 256 thr, M=64, N=256. Grid (32,4).
__global__ __launch_bounds__(256) void xu_kernel(
    const int* __restrict__ tokp, const float* __restrict__ embp,
    const float* __restrict__ uF, const float* __restrict__ uI,
    const float* __restrict__ uC, const float* __restrict__ uO,
    float* __restrict__ XU, u32* __restrict__ cnt)
{
  const int tid = threadIdx.x;
  if (blockIdx.x == 0 && blockIdx.y == 0 && tid < NLAYER * SEQ) cnt[tid] = 0u;

  const int lane = tid & 63, wv = tid >> 6, r16 = lane & 15, kgrp = lane >> 4;
  const int m0 = blockIdx.x * 64;
  const int n0 = blockIdx.y * 256 + wv * 64;
  const float* Ug[4] = {uF, uI, uC, uO};

  bf16x8 b[4][8];
#pragma unroll
  for (int nt = 0; nt < 4; ++nt) {
    const int n = n0 + nt * 16 + r16;
    const float* U = Ug[n >> 8];
    const int c = n & 255;
#pragma unroll
    for (int kk = 0; kk < 8; ++kk) {
      const int kb = kk * 32 + kgrp * 8;
      bf16x8 v;
#pragma unroll
      for (int e = 0; e < 8; ++e) v[e] = (__bf16)U[(size_t)(kb + e) * HID + c];
      b[nt][kk] = v;
    }
  }

  for (int mi = 0; mi < 4; ++mi) {
    const int tok = tokp[m0 + mi * 16 + r16];
    const float* x = embp + (size_t)tok * DIM;
    bf16x8 a[8];
#pragma unroll
    for (int kk = 0; kk < 8; ++kk) {
      const int kb = kk * 32 + kgrp * 8;
      const float4 u0 = *reinterpret_cast<const float4*>(x + kb);
      const float4 u1 = *reinterpret_cast<const float4*>(x + kb + 4);
      bf16x8 v;
      v[0] = (__bf16)u0.x; v[1] = (__bf16)u0.y; v[2] = (__bf16)u0.z; v[3] = (__bf16)u0.w;
      v[4] = (__bf16)u1.x; v[5] = (__bf16)u1.y; v[6] = (__bf16)u1.z; v[7] = (__bf16)u1.w;
      a[kk] = v;
    }
#pragma unroll
    for (int nt = 0; nt < 4; ++nt) {
      f32x4 acc = {0.f, 0.f, 0.f, 0.f};
#pragma unroll
      for (int kk = 0; kk < 8; ++kk)
        acc = __builtin_amdgcn_mfma_f32_16x16x32_bf16(a[kk], b[nt][kk], acc, 0, 0, 0);
      const int n = n0 + nt * 16 + r16;
#pragma unroll
      for (int r = 0; r < 4; ++r)
        XU[(size_t)(m0 + mi * 16 + kgrp * 4 + r) * 1024 + n] = acc[r];
    }
  }
}

// ---------------- persistent LSTM ----------------
// 8 WGs x 512 thr. WG bx: layer l=bx>>2, col-slice jj=bx&3 (64 cols/gate).
// Wave wv: gate=wv>>1, half=wv&1. Weights in registers as MFMA B-fragments.
// h histories in bf16; cross-WG h via write-through relaxed-agent stores;
// sync = one counter per (l,t), relaxed poll + single acquire fence per step.
__global__ __launch_bounds__(512, 1) void lstm_kernel(
    const float* __restrict__ wF, const float* __restrict__ uF, const float* __restrict__ bF,
    const float* __restrict__ wI, const float* __restrict__ uI, const float* __restrict__ bI,
    const float* __restrict__ wC, const float* __restrict__ uC, const float* __restrict__ bC,
    const float* __restrict__ wO, const float* __restrict__ uO, const float* __restrict__ bO,
    const float* __restrict__ XU, u16* __restrict__ h0b, u16* __restrict__ h1b,
    u32* __restrict__ cnt, float* __restrict__ dout)
{
  const int tid  = threadIdx.x;
  const int lane = tid & 63;
  const int wv   = tid >> 6;
  const int bx   = blockIdx.x;
  const int l    = bx >> 2;
  const int jj   = bx & 3;
  const int gate = wv >> 1;
  const int r16  = lane & 15;
  const int kgrp = lane >> 4;

  const float* Wg[4] = {wF, wI, wC, wO};
  const float* Ug[4] = {uF, uI, uC, uO};
  const float* Bg[4] = {bF, bI, bC, bO};

  // B fragments: kk 0..7 = W (h-part); for l==1 kk 8..15 = U (x = h0 part)
  bf16x8 bw[2][16];
  float bias[2];
  {
    const float* W = Wg[gate];
    const float* U = Ug[gate];
#pragma unroll
    for (int nt = 0; nt < 2; ++nt) {
      const int n = jj * 64 + (wv & 1) * 32 + nt * 16 + r16;
      bias[nt] = Bg[gate][n];
#pragma unroll
      for (int kk = 0; kk < 8; ++kk) {
        const int kb = kk * 32 + kgrp * 8;
        bf16x8 v;
#pragma unroll
        for (int e = 0; e < 8; ++e) v[e] = (__bf16)W[(size_t)(kb + e) * HID + n];
        bw[nt][kk] = v;
      }
      if (l == 1) {
#pragma unroll
        for (int kk = 0; kk < 8; ++kk) {
          const int kb = kk * 32 + kgrp * 8;
          bf16x8 v;
#pragma unroll
          for (int e = 0; e < 8; ++e) v[e] = (__bf16)U[(size_t)(kb + e) * HID + n];
          bw[nt][kk + 8] = v;
        }
      }
    }
  }

  __shared__ float gbuf[4][16][66];

  const int eb = tid >> 5;
  const int ec = (tid & 31) * 2;
  float c0 = 0.f, c1 = 0.f;

  const int ncol0 = gate * 256 + jj * 64 + (wv & 1) * 32 + r16;  // XU col for nt=0

  for (int t = 0; t < SEQ; ++t) {
    // ---- wait for producers ----
    if (tid == 0) {
      if (l == 0) {
        if (t > 0)
          while (__hip_atomic_load(&cnt[t - 1], __ATOMIC_RELAXED, __HIP_MEMORY_SCOPE_AGENT) < 4u)
            __builtin_amdgcn_s_sleep(1);
      } else {
        if (t > 0)
          while (__hip_atomic_load(&cnt[SEQ + t - 1], __ATOMIC_RELAXED, __HIP_MEMORY_SCOPE_AGENT) < 4u)
            __builtin_amdgcn_s_sleep(1);
        while (__hip_atomic_load(&cnt[t], __ATOMIC_RELAXED, __HIP_MEMORY_SCOPE_AGENT) < 4u)
          __builtin_amdgcn_s_sleep(1);
      }
      if (t > 0 || l == 1)
        __builtin_amdgcn_fence(__ATOMIC_ACQUIRE, "agent");
    }
    __syncthreads();

    f32x4 acc0 = {0.f, 0.f, 0.f, 0.f};
    f32x4 acc1 = {0.f, 0.f, 0.f, 0.f};

    float xu0[4], xu1[4];
    if (l == 0) {
      const float* xp = XU + (size_t)t * BATCH * 1024;
#pragma unroll
      for (int r = 0; r < 4; ++r) {
        xu0[r] = xp[(size_t)(kgrp * 4 + r) * 1024 + ncol0];
        xu1[r] = xp[(size_t)(kgrp * 4 + r) * 1024 + ncol0 + 16];
      }
    }

    if (l == 0) {
      if (t > 0) {
        const u16* hb = h0b + ((size_t)(t - 1) * BATCH + r16) * HID + kgrp * 8;
#pragma unroll
        for (int kk = 0; kk < 8; ++kk) {
          const bf16x8 a = *reinterpret_cast<const bf16x8*>(hb + kk * 32);
          acc0 = __builtin_amdgcn_mfma_f32_16x16x32_bf16(a, bw[0][kk], acc0, 0, 0, 0);
          acc1 = __builtin_amdgcn_mfma_f32_16x16x32_bf16(a, bw[1][kk], acc1, 0, 0, 0);
        }
      }
    } else {
      if (t > 0) {
        const u16* hb = h1b + ((size_t)(t - 1) * BATCH + r16) * HID + kgrp * 8;
#pragma unroll
        for (int kk = 0; kk < 8; ++kk) {
          const bf16x8 a = *reinterpret_cast<const bf16x8*>(hb + kk * 32);
          acc0 = __builtin_amdgcn_mfma_f32_16x16x32_bf16(a, bw[0][kk], acc0, 0, 0, 0);
          acc1 = __builtin_amdgcn_mfma_f32_16x16x32_bf16(a, bw[1][kk], acc1, 0, 0, 0);
        }
      }
      const u16* xb = h0b + ((size_t)t * BATCH + r16) * HID + kgrp * 8;
#pragma unroll
      for (int kk = 0; kk < 8; ++kk) {
        const bf16x8 a = *reinterpret_cast<const bf16x8*>(xb + kk * 32);
        acc0 = __builtin_amdgcn_mfma_f32_16x16x32_bf16(a, bw[0][kk + 8], acc0, 0, 0, 0);
        acc1 = __builtin_amdgcn_mfma_f32_16x16x32_bf16(a, bw[1][kk + 8], acc1, 0, 0, 0);
      }
    }

    // ---- activations -> LDS ----
#pragma unroll
    for (int nt = 0; nt < 2; ++nt) {
      const f32x4 acc = nt ? acc1 : acc0;
      const float* xu = nt ? xu1 : xu0;
      const int c = (wv & 1) * 32 + nt * 16 + r16;
#pragma unroll
      for (int r = 0; r < 4; ++r) {
        float z = acc[r] + bias[nt];
        if (l == 0) z += xu[r];
        const float act = (gate == 2) ? tanhf(z) : 1.f / (1.f + expf(-z));
        gbuf[gate][kgrp * 4 + r][c] = act;
      }
    }
    __syncthreads();

    // ---- c/h update ----
    const float ff0 = gbuf[0][eb][ec], ff1 = gbuf[0][eb][ec + 1];
    const float ii0 = gbuf[1][eb][ec], ii1 = gbuf[1][eb][ec + 1];
    const float gg0 = gbuf[2][eb][ec], gg1 = gbuf[2][eb][ec + 1];
    const float oo0 = gbuf[3][eb][ec], oo1 = gbuf[3][eb][ec + 1];
    c0 = ff0 * c0 + ii0 * gg0;
    c1 = ff1 * c1 + ii1 * gg1;
    const float hv0 = oo0 * tanhf(c0);
    const float hv1 = oo1 * tanhf(c1);
    const int n = jj * 64 + ec;

    u16* hbase = (l == 0) ? h0b : h1b;
    const u32 pk = (u32)__builtin_bit_cast(u16, (__bf16)hv0) |
                   ((u32)__builtin_bit_cast(u16, (__bf16)hv1) << 16);
    __hip_atomic_store(reinterpret_cast<u32*>(hbase + ((size_t)t * BATCH + eb) * HID + n),
                       pk, __ATOMIC_RELAXED, __HIP_MEMORY_SCOPE_AGENT);

    if (t == SEQ - 1) {
      const size_t logitsN = (size_t)SEQ * BATCH * NVOC;
      float* hT = dout + logitsN + ((size_t)l * BATCH + eb) * HID + n;
      float* cT = dout + logitsN + (size_t)NLAYER * BATCH * HID + ((size_t)l * BATCH + eb) * HID + n;
      hT[0] = hv0; hT[1] = hv1;
      cT[0] = c0;  cT[1] = c1;
    }
    __syncthreads();
    if (tid == 0)
      __hip_atomic_fetch_add(&cnt[l * SEQ + t], 1u, __ATOMIC_RELEASE, __HIP_MEMORY_SCOPE_AGENT);
  }
}

// ---------------- decoder: logits = h_top @ dec_w^T + dec_b ----------------
// M=32 per block (2 m-tiles), 4 waves x 64 N-cols, K=256. Grid (64, 197).
__global__ __launch_bounds__(256) void dec_kernel(
    const u16* __restrict__ htb, const u16* __restrict__ dwb,
    const float* __restrict__ dbp, float* __restrict__ out)
{
  const int tid  = threadIdx.x;
  const int lane = tid & 63;
  const int wv   = tid >> 6;
  const int r16  = lane & 15;
  const int kgrp = lane >> 4;
  const int m0 = blockIdx.x * 32;
  const int n0 = blockIdx.y * 256 + wv * 64;

  bf16x8 a[2][8];
#pragma unroll
  for (int mt = 0; mt < 2; ++mt) {
    const u16* ap = htb + ((size_t)(m0 + mt * 16 + r16)) * HID + kgrp * 8;
#pragma unroll
    for (int kk = 0; kk < 8; ++kk)
      a[mt][kk] = *reinterpret_cast<const bf16x8*>(ap + kk * 32);
  }

  f32x4 acc[2][4];
#pragma unroll
  for (int mt = 0; mt < 2; ++mt)
#pragma unroll
    for (int nt = 0; nt < 4; ++nt) {
      acc[mt][nt][0] = 0.f; acc[mt][nt][1] = 0.f;
      acc[mt][nt][2] = 0.f; acc[mt][nt][3] = 0.f;
    }

#pragma unroll
  for (int nt = 0; nt < 4; ++nt) {
    const int v = n0 + nt * 16 + r16;
    const int vc = (v < NVOC) ? v : 0;
    const u16* bp = dwb + (size_t)vc * HID + kgrp * 8;
#pragma unroll
    for (int kk = 0; kk < 8; ++kk) {
      const bf16x8 b = *reinterpret_cast<const bf16x8*>(bp + kk * 32);
      acc[0][nt] = __builtin_amdgcn_mfma_f32_16x16x32_bf16(a[0][kk], b, acc[0][nt], 0, 0, 0);
      acc[1][nt] = __builtin_amdgcn_mfma_f32_16x16x32_bf16(a[1][kk], b, acc[1][nt], 0, 0, 0);
    }
  }

#pragma unroll
  for (int nt = 0; nt < 4; ++nt) {
    const int v = n0 + nt * 16 + r16;
    if (v < NVOC) {
      const float bb = dbp[v];
#pragma unroll
      for (int mt = 0; mt < 2; ++mt)
#pragma unroll
        for (int r = 0; r < 4; ++r)
          out[(size_t)(m0 + mt * 16 + kgrp * 4 + r) * NVOC + v] = acc[mt][nt][r] + bb;
    }
  }
}

extern "C" void kernel_launch(void* const* d_in, const int* in_sizes, int n_in,
                              void* d_out, int out_size, void* d_ws, size_t ws_size,
                              hipStream_t stream) {
  const int*   tokp = (const int*)d_in[0];
  const float* embp = (const float*)d_in[1];
  const float* wF = (const float*)d_in[2];
  const float* uF = (const float*)d_in[3];
  const float* bF = (const float*)d_in[4];
  const float* wI = (const float*)d_in[5];
  const float* uI = (const float*)d_in[6];
  const float* bI = (const float*)d_in[7];
  const float* wC = (const float*)d_in[8];
  const float* uC = (const float*)d_in[9];
  const float* bC = (const float*)d_in[10];
  const float* wO = (const float*)d_in[11];
  const float* uO = (const float*)d_in[12];
  const float* bO = (const float*)d_in[13];
  const float* dw = (const float*)d_in[14];
  const float* db = (const float*)d_in[15];
  float* out = (float*)d_out;

  char* ws = (char*)d_ws;
  size_t off = 0;
  // region A: XU (8 MB, alive during lstm) aliased with dwb (25.7 MB, alive during dec)
  char* regionA = ws;
  off += (size_t)NVOC * HID * 2;               // 25.7 MB (covers XU's 8 MB too)
  off = (off + 255) & ~(size_t)255;
  u16* h0b = (u16*)(ws + off); off += (size_t)SEQ * BATCH * HID * 2;
  u16* h1b = (u16*)(ws + off); off += (size_t)SEQ * BATCH * HID * 2;
  u32* cnt = (u32*)(ws + off); off += (size_t)NLAYER * SEQ * 4;

  float* XU  = (float*)regionA;
  u16*   dwb = (u16*)regionA;

  // order matters: xu (writes XU, zeroes cnt) -> lstm (reads XU) ->
  // prep (overwrites region A with dwb) -> dec (reads dwb)
  xu_kernel<<<dim3(32, 4), 256, 0, stream>>>(tokp, embp, uF, uI, uC, uO, XU, cnt);
  lstm_kernel<<<8, 512, 0, stream>>>(wF, uF, bF, wI, uI, bI, wC, uC, bC, wO, uO, bO,
                                     XU, h0b, h1b, cnt, out);
  prep_kernel<<<1024, 256, 0, stream>>>(dw, dwb, NVOC * HID / 4);
  dec_kernel<<<dim3(64, (NVOC + 255) / 256), 256, 0, stream>>>(h1b, dwb, db, out);
}